// Round 15
// baseline (25.966 us; speedup 1.0000x reference)
//
#include <hip/hip_runtime.h>
#include <math.h>

#define B_ 4096
#define D_ 256
#define C_ 64
#define BD (B_*D_)

typedef __attribute__((ext_vector_type(8))) short bf16x8;
typedef __attribute__((ext_vector_type(4))) float f32x4;

__device__ __forceinline__ float wave_reduce_sum(float v) {
    #pragma unroll
    for (int off = 1; off < 64; off <<= 1) v += __shfl_xor(v, off);
    return v;
}

__device__ __forceinline__ unsigned cvtpk(float lo, float hi) {
    unsigned r;
    asm volatile("v_cvt_pk_bf16_f32 %0, %1, %2" : "=v"(r) : "v"(lo), "v"(hi));
    return r;
}

// ---- MFMA kernel: grid = 64 conds x 4 col-quarters x 2 sample-halves = 512 (2/CU) ----
// Block (cond,ct,sl): y[samples = sl (mod 2) of cond, cols ct*64..+63].
// W quarter staged to LDS ONCE (single barrier); K-loop barrier-free.
__global__ __launch_bounds__(256, 2) void k_main(const float* __restrict__ W,
                                                 const float* __restrict__ b,
                                                 const float* __restrict__ x,
                                                 const int* __restrict__ c,
                                                 float* __restrict__ out,
                                                 float* __restrict__ l1p,
                                                 float* __restrict__ xsqp,
                                                 int* __restrict__ cnt2) {
    int hw = blockIdx.x;
    int bid = (hw & 7) * 64 + (hw >> 3);    // XCD swizzle: a cond's 8 blocks share an XCD
    int cond = bid >> 3;
    int ct = (bid >> 1) & 3;
    int sl = bid & 1;
    int tid = threadIdx.x;
    int wv = tid >> 6, lane = tid & 63;
    int g = lane >> 4, fr = lane & 15;
    int r = tid >> 2, q = tid & 3;          // W staging: row 0..63, quarter 0..3 (64 floats)

    // ---- early independent loads: x stripe, c, W quarter, bias ----
    const float4* x4 = (const float4*)x;
    int xi = bid * 512 + tid;               // 512 float4 per block
    float4 xv0 = x4[xi];
    float4 xv1 = x4[xi + 256];
    const int4* c4 = (const int4*)c;
    int4 cq[4];
    cq[0] = c4[2 * tid];     cq[1] = c4[2 * tid + 1];
    cq[2] = c4[2 * tid + 512]; cq[3] = c4[2 * tid + 513];
    // this thread's W: row (ct*64 + r), floats q*64 .. q*64+63 (fully coalesced per block)
    const float4* Wt4 = (const float4*)(W + (size_t)cond * 65536) + (size_t)(ct * 64 + r) * 64 + q * 16;
    float4 wr[16];
    #pragma unroll
    for (int j = 0; j < 16; ++j) wr[j] = Wt4[j];
    float bias_s = b[cond * 256 + ct * 64 + wv * 16 + fr];

    __shared__ unsigned Xl[64 * 128];        // 64 samples x 512B bf16 (XOR swizzled) = 32KB
    __shared__ unsigned Wf[64 * 132];        // W quarter bf16: 64 rows x 528B (128 data + 4 pad words) = 33KB
    __shared__ float part_x[4];
    __shared__ float part_w[4];
    __shared__ int slist[64];
    __shared__ int nlist;
    if (tid == 0) nlist = 0;

    // ---- x copy to out tail + sumsq partial ----
    float2* dst = (float2*)(out + BD + 2);
    dst[2 * xi]             = make_float2(xv0.x, xv0.y);
    dst[2 * xi + 1]         = make_float2(xv0.z, xv0.w);
    dst[2 * (xi + 256)]     = make_float2(xv1.x, xv1.y);
    dst[2 * (xi + 256) + 1] = make_float2(xv1.z, xv1.w);
    float s = xv0.x * xv0.x + xv0.y * xv0.y + xv0.z * xv0.z + xv0.w * xv0.w
            + xv1.x * xv1.x + xv1.y * xv1.y + xv1.z * xv1.z + xv1.w * xv1.w;
    s = wave_reduce_sum(s);
    if (lane == 0) part_x[wv] = s;
    __syncthreads();                         // bar 1: nlist init + part_x visible

    // ---- scan: slice sl owns samples i == sl (mod 2); 8 candidates/thread ----
    #pragma unroll
    for (int t = 0; t < 4; ++t) {
        int s0 = (t < 2) ? (8 * tid + 4 * t) : (2048 + 8 * tid + 4 * (t - 2));
        int a  = sl ? cq[t].y : cq[t].x;
        int b2 = sl ? cq[t].w : cq[t].z;
        if (a == cond)  { int p = atomicAdd(&nlist, 1); if (p < 64) slist[p] = s0 + sl; }
        if (b2 == cond) { int p = atomicAdd(&nlist, 1); if (p < 64) slist[p] = s0 + 2 + sl; }
    }
    __syncthreads();                         // bar 2: slist ready
    int n = min(nlist, 64);
    int mts = (n + 15) >> 4;                 // 0..4 sample-tiles
    if (tid == 0) {
        xsqp[bid] = (part_x[0] + part_x[1]) + (part_x[2] + part_x[3]);
        if (ct == 0) cnt2[cond * 2 + sl] = n;
    }

    // ---- stage X: batched gather (sample ids pre-read; all loads in flight) ----
    int sgr[16];
    #pragma unroll
    for (int k = 0; k < 16; ++k) sgr[k] = slist[wv + 4 * k];
    #pragma unroll
    for (int k = 0; k < 16; ++k) {
        int u = tid + 256 * k;
        if (u < n * 64) {
            int si = u >> 6, v = u & 63;
            float4 qv = x4[(size_t)sgr[k] * 64 + v];
            int off = (v * 8) ^ ((si & 7) << 4);          // 16B-granule XOR swizzle
            uint2 pk = make_uint2(cvtpk(qv.x, qv.y), cvtpk(qv.z, qv.w));
            *(uint2*)(Xl + si * 128 + (off >> 2)) = pk;
        }
    }

    // ---- stage W quarter: full 64x256 bf16, one pass ----
    float l1acc = 0.f;
    #pragma unroll
    for (int jj = 0; jj < 8; ++jj) {
        uint4 pk;
        pk.x = cvtpk(wr[2*jj].x,   wr[2*jj].y);
        pk.y = cvtpk(wr[2*jj].z,   wr[2*jj].w);
        pk.z = cvtpk(wr[2*jj+1].x, wr[2*jj+1].y);
        pk.w = cvtpk(wr[2*jj+1].z, wr[2*jj+1].w);
        *(uint4*)(&Wf[r * 132 + q * 32 + jj * 4]) = pk;
    }
    if (sl == 0) {
        #pragma unroll
        for (int j = 0; j < 16; ++j)
            l1acc += fabsf(wr[j].x) + fabsf(wr[j].y) + fabsf(wr[j].z) + fabsf(wr[j].w);
    }
    __syncthreads();                         // bar 3: Xl + Wf ready

    // ---- K loop: 8 slabs, barrier-free ----
    f32x4 acc[4];
    #pragma unroll
    for (int mt = 0; mt < 4; ++mt) acc[mt] = (f32x4){0.f, 0.f, 0.f, 0.f};

    #pragma unroll
    for (int kk = 0; kk < 8; ++kk) {
        bf16x8 bfr = *(const bf16x8*)(Wf + (wv * 16 + fr) * 132 + kk * 32 + g * 4);
        #pragma unroll
        for (int mt = 0; mt < 4; ++mt) if (mt < mts) {
            int row = mt * 16 + fr;
            bf16x8 afr = *(const bf16x8*)((const char*)Xl + row * 512 + ((kk * 64 + g * 16) ^ ((row & 7) << 4)));
            acc[mt] = __builtin_amdgcn_mfma_f32_16x16x32_bf16(afr, bfr, acc[mt], 0, 0, 0);
        }
    }

    // ---- W L1 partial (sl==0 blocks; (cond,ct) quarters disjoint) ----
    if (sl == 0) {
        float a = wave_reduce_sum(l1acc);
        if (lane == 0) part_w[wv] = a;
    }
    __syncthreads();                         // bar 4
    if (sl == 0 && tid == 0)
        l1p[cond * 4 + ct] = (part_w[0] + part_w[1]) + (part_w[2] + part_w[3]);

    // ---- bias add + store unnormalized y ----
    #pragma unroll
    for (int mt = 0; mt < 4; ++mt) if (mt < mts) {
        #pragma unroll
        for (int j = 0; j < 4; ++j) {
            int row = mt * 16 + g * 4 + j;
            if (row < n) {
                int sg = slist[row];
                out[(size_t)sg * 256 + ct * 64 + wv * 16 + fr] = acc[mt][j] + bias_s;
            }
        }
    }
}

// ---- blocks 0..1023: row L2-normalize (wave per row) ----
// ---- block 1024: finalize embed_norm and mask_norm ----
__global__ __launch_bounds__(256) void k_fin(float* __restrict__ out,
                                             const float* __restrict__ xsqp,
                                             const float* __restrict__ l1p,
                                             const int* __restrict__ cnt2) {
    int tid = threadIdx.x;
    int wv = tid >> 6, lane = tid & 63;
    if (blockIdx.x == 1024) {
        __shared__ float part[4];
        float s = xsqp[tid] + xsqp[tid + 256];
        s = wave_reduce_sum(s);
        if (lane == 0) part[wv] = s;
        __syncthreads();
        if (tid < 64) {
            float l1 = (l1p[tid * 4 + 0] + l1p[tid * 4 + 1]) + (l1p[tid * 4 + 2] + l1p[tid * 4 + 3]);
            float cnt = (float)(cnt2[tid * 2] + cnt2[tid * 2 + 1]);
            float mv = l1 * cnt;
            mv = wave_reduce_sum(mv);
            if (tid == 0) out[BD] = mv;                                               // mask_norm
        }
        if (tid == 0) out[BD + 1] = sqrtf((part[0] + part[1]) + (part[2] + part[3])); // embed_norm
        return;
    }
    int rowv = blockIdx.x * 4 + wv;          // 4096 rows, wave per row
    float4* p = (float4*)out + (size_t)rowv * 64 + lane;
    float4 v = *p;
    float s = v.x * v.x + v.y * v.y + v.z * v.z + v.w * v.w;
    s = wave_reduce_sum(s);
    float inv = 1.0f / fmaxf(sqrtf(s), 1e-10f);
    v.x *= inv; v.y *= inv; v.z *= inv; v.w *= inv;
    *p = v;
}

extern "C" void kernel_launch(void* const* d_in, const int* in_sizes, int n_in,
                              void* d_out, int out_size, void* d_ws, size_t ws_size,
                              hipStream_t stream) {
    const float* x = (const float*)d_in[0];
    const float* W = (const float*)d_in[1];
    const float* b = (const float*)d_in[2];
    const int*   c = (const int*)d_in[3];
    float* out = (float*)d_out;

    float* xsqp = (float*)d_ws;           // 512
    float* l1p  = xsqp + 512;             // 256
    int*   cnt2 = (int*)(l1p + 256);      // 128

    k_main<<<512, 256, 0, stream>>>(W, b, x, c, out, l1p, xsqp, cnt2);
    k_fin<<<1025, 256, 0, stream>>>(out, xsqp, l1p, cnt2);
}

// Round 16
// 18.761 us; speedup vs baseline: 1.3841x; 1.3841x over previous
//
#include <hip/hip_runtime.h>
#include <math.h>

#define B_ 4096
#define D_ 256
#define C_ 64
#define BD (B_*D_)

typedef __attribute__((ext_vector_type(8))) short bf16x8;
typedef __attribute__((ext_vector_type(4))) float f32x4;

__device__ __forceinline__ float wave_reduce_sum(float v) {
    #pragma unroll
    for (int off = 1; off < 64; off <<= 1) v += __shfl_xor(v, off);
    return v;
}

__device__ __forceinline__ unsigned cvtpk(float lo, float hi) {
    unsigned r;
    asm volatile("v_cvt_pk_bf16_f32 %0, %1, %2" : "=v"(r) : "v"(lo), "v"(hi));
    return r;
}

// ---- MFMA kernel: grid = 64 conds x 8 col-eighths x 2 sample-halves = 1024 (4/CU) ----
// Block (cond,ct,sl): y[samples = sl (mod 2) of cond, cols ct*32..+31].
// Waves: (wv&1) = col half (16 cols), (wv>>1) = sample-row half (32 rows).
__global__ __launch_bounds__(256, 4) void k_main(const float* __restrict__ W,
                                                 const float* __restrict__ b,
                                                 const float* __restrict__ x,
                                                 const int* __restrict__ c,
                                                 float* __restrict__ out,
                                                 float* __restrict__ l1p,
                                                 float* __restrict__ xsqp,
                                                 int* __restrict__ cnt2) {
    int hw = blockIdx.x;
    int bid = (hw & 7) * 128 + (hw >> 3);   // XCD swizzle: a cond's 16 blocks share an XCD
    int cond = bid >> 4;
    int ct = (bid >> 1) & 7;
    int sl = bid & 1;
    int tid = threadIdx.x;
    int wv = tid >> 6, lane = tid & 63;
    int g = lane >> 4, fr = lane & 15;
    int cw = wv & 1, rh = wv >> 1;          // col half / row half
    int r = tid >> 3, ch = tid & 7;         // W staging: row 0..31, 4-float chunk 0..7

    // ---- early independent loads: x stripe, c, W slabs 0..1, bias ----
    const float4* x4 = (const float4*)x;
    int xi = bid * 256 + tid;               // 1 float4 per thread
    float4 xv = x4[xi];
    int4 cvq[4];
    #pragma unroll
    for (int t = 0; t < 4; ++t) cvq[t] = ((const int4*)c)[t * 256 + tid];
    // thread stages W row (ct*32 + r), slab kk floats kk*32 + ch*4
    const float4* Wt4 = (const float4*)(W + (size_t)cond * 65536) + (size_t)(ct * 32 + r) * 64 + ch;
    float4 wA = Wt4[0];                     // slab 0
    float4 wB = Wt4[8];                     // slab 1
    float bias_s = b[cond * 256 + ct * 32 + cw * 16 + fr];

    __shared__ unsigned Xl[64 * 128];        // 64 samples x 512B bf16 (XOR swizzled) = 32KB
    __shared__ unsigned Wl[2][32 * 20];      // dbuf W slab: 32 rows x 80B = 5KB
    __shared__ float part_x[4];
    __shared__ float part_w[4];
    __shared__ int slist[64];
    __shared__ int nlist;
    if (tid == 0) nlist = 0;

    // ---- x copy to out tail + sumsq partial ----
    float2* dst = (float2*)(out + BD + 2);
    dst[2 * xi]     = make_float2(xv.x, xv.y);
    dst[2 * xi + 1] = make_float2(xv.z, xv.w);
    float s = xv.x * xv.x + xv.y * xv.y + xv.z * xv.z + xv.w * xv.w;
    s = wave_reduce_sum(s);
    if (lane == 0) part_x[wv] = s;
    __syncthreads();                         // bar 1: nlist init + part_x visible

    // ---- scan: slice sl owns samples i == sl (mod 2); 8 candidates/thread ----
    #pragma unroll
    for (int t = 0; t < 4; ++t) {
        int4 q = cvq[t];
        int base = 4 * (t * 256 + tid);
        int a  = sl ? q.y : q.x;
        int b2 = sl ? q.w : q.z;
        if (a == cond)  { int p = atomicAdd(&nlist, 1); if (p < 64) slist[p] = base + sl; }
        if (b2 == cond) { int p = atomicAdd(&nlist, 1); if (p < 64) slist[p] = base + 2 + sl; }
    }
    __syncthreads();                         // bar 2: slist ready
    int n = min(nlist, 64);
    int mts = (n + 15) >> 4;                 // 0..4 sample-tiles (block-wide)
    if (tid == 0) {
        xsqp[bid] = (part_x[0] + part_x[1]) + (part_x[2] + part_x[3]);
        if (ct == 0) cnt2[cond * 2 + sl] = n;
    }

    // ---- stage X: batched gather (sample ids pre-read; loads in flight) ----
    int sgr[16];
    #pragma unroll
    for (int k = 0; k < 16; ++k) sgr[k] = slist[wv + 4 * k];
    #pragma unroll
    for (int k = 0; k < 16; ++k) {
        int u = tid + 256 * k;
        if (u < n * 64) {
            int si = u >> 6, v = u & 63;
            float4 qv = x4[(size_t)sgr[k] * 64 + v];
            int off = (v * 8) ^ ((si & 7) << 4);          // 16B-granule XOR swizzle
            uint2 pk = make_uint2(cvtpk(qv.x, qv.y), cvtpk(qv.z, qv.w));
            *(uint2*)(Xl + si * 128 + (off >> 2)) = pk;
        }
    }

    // ---- stage W slab0 -> buf0 ----
    float l1acc = 0.f;
    {
        uint2 pk = make_uint2(cvtpk(wA.x, wA.y), cvtpk(wA.z, wA.w));
        *(uint2*)(&Wl[0][r * 20 + ch * 2]) = pk;
        if (sl == 0)
            l1acc += fabsf(wA.x) + fabsf(wA.y) + fabsf(wA.z) + fabsf(wA.w);
    }
    __syncthreads();                         // bar 3: Xl + Wl[0] ready

    // ---- K loop: 8 slabs, double-buffered ----
    f32x4 acc[2];
    acc[0] = (f32x4){0.f, 0.f, 0.f, 0.f};
    acc[1] = (f32x4){0.f, 0.f, 0.f, 0.f};

    #pragma unroll
    for (int kk = 0; kk < 8; ++kk) {
        bf16x8 bfr = *(const bf16x8*)(&Wl[kk & 1][(cw * 16 + fr) * 20 + g * 4]);
        #pragma unroll
        for (int mt = 0; mt < 2; ++mt) if (rh * 2 + mt < mts) {
            int row = rh * 32 + mt * 16 + fr;
            bf16x8 afr = *(const bf16x8*)((const char*)Xl + row * 512 + ((kk * 64 + g * 16) ^ ((row & 7) << 4)));
            acc[mt] = __builtin_amdgcn_mfma_f32_16x16x32_bf16(afr, bfr, acc[mt], 0, 0, 0);
        }
        if (kk < 7) {
            float4 wsrc = (kk & 1) ? wA : wB;              // slab kk+1 regs
            uint2 pk = make_uint2(cvtpk(wsrc.x, wsrc.y), cvtpk(wsrc.z, wsrc.w));
            *(uint2*)(&Wl[(kk + 1) & 1][r * 20 + ch * 2]) = pk;
            if (sl == 0)
                l1acc += fabsf(wsrc.x) + fabsf(wsrc.y) + fabsf(wsrc.z) + fabsf(wsrc.w);
            if (kk < 6) {
                if (kk & 1) wB = Wt4[(kk + 2) * 8];
                else        wA = Wt4[(kk + 2) * 8];
            }
            __syncthreads();
        }
    }

    // ---- W L1 partial (sl==0 blocks; (cond,ct) eighths disjoint) ----
    if (sl == 0) {
        float a = wave_reduce_sum(l1acc);
        if (lane == 0) part_w[wv] = a;
    }
    __syncthreads();                         // bar 4
    if (sl == 0 && tid == 0)
        l1p[cond * 8 + ct] = (part_w[0] + part_w[1]) + (part_w[2] + part_w[3]);

    // ---- bias add + store unnormalized y ----
    #pragma unroll
    for (int mt = 0; mt < 2; ++mt) if (rh * 2 + mt < mts) {
        #pragma unroll
        for (int j = 0; j < 4; ++j) {
            int row = rh * 32 + mt * 16 + g * 4 + j;
            if (row < n) {
                int sg = slist[row];
                out[(size_t)sg * 256 + ct * 32 + cw * 16 + fr] = acc[mt][j] + bias_s;
            }
        }
    }
}

// ---- blocks 0..1023: row L2-normalize (wave per row) ----
// ---- block 1024: finalize embed_norm and mask_norm ----
__global__ __launch_bounds__(256) void k_fin(float* __restrict__ out,
                                             const float* __restrict__ xsqp,
                                             const float* __restrict__ l1p,
                                             const int* __restrict__ cnt2) {
    int tid = threadIdx.x;
    int wv = tid >> 6, lane = tid & 63;
    if (blockIdx.x == 1024) {
        __shared__ float part[4];
        float s = 0.f;
        #pragma unroll
        for (int j = 0; j < 4; ++j) s += xsqp[tid * 4 + j];
        s = wave_reduce_sum(s);
        if (lane == 0) part[wv] = s;
        __syncthreads();
        if (tid < 64) {
            float l1 = 0.f;
            #pragma unroll
            for (int j = 0; j < 8; ++j) l1 += l1p[tid * 8 + j];
            float cnt = (float)(cnt2[tid * 2] + cnt2[tid * 2 + 1]);
            float mv = l1 * cnt;
            mv = wave_reduce_sum(mv);
            if (tid == 0) out[BD] = mv;                                               // mask_norm
        }
        if (tid == 0) out[BD + 1] = sqrtf((part[0] + part[1]) + (part[2] + part[3])); // embed_norm
        return;
    }
    int rowv = blockIdx.x * 4 + wv;          // 4096 rows, wave per row
    float4* p = (float4*)out + (size_t)rowv * 64 + lane;
    float4 v = *p;
    float s = v.x * v.x + v.y * v.y + v.z * v.z + v.w * v.w;
    s = wave_reduce_sum(s);
    float inv = 1.0f / fmaxf(sqrtf(s), 1e-10f);
    v.x *= inv; v.y *= inv; v.z *= inv; v.w *= inv;
    *p = v;
}

extern "C" void kernel_launch(void* const* d_in, const int* in_sizes, int n_in,
                              void* d_out, int out_size, void* d_ws, size_t ws_size,
                              hipStream_t stream) {
    const float* x = (const float*)d_in[0];
    const float* W = (const float*)d_in[1];
    const float* b = (const float*)d_in[2];
    const int*   c = (const int*)d_in[3];
    float* out = (float*)d_out;

    float* xsqp = (float*)d_ws;           // 1024
    float* l1p  = xsqp + 1024;            // 512
    int*   cnt2 = (int*)(l1p + 512);      // 128

    k_main<<<1024, 256, 0, stream>>>(W, b, x, c, out, l1p, xsqp, cnt2);
    k_fin<<<1025, 256, 0, stream>>>(out, xsqp, l1p, cnt2);
}